// Round 4
// baseline (375.786 us; speedup 1.0000x reference)
//
#include <hip/hip_runtime.h>

// TSK fuzzy model forward.  N=32768 rows, D=64 dims, R=32 rules.
// R8: register-fed store stream + quad-interleaved constants.
// History: R5 split FAILED (structure not limiter).  R6 nt NEUTRAL (no RFO).
// R7 b128 phase-1 reads +10us (partial: stride-68 layout was 4-way bank
// aliased, and phase-2's 130 ds_read_b32/wave remained).  Accounting: LDS
// pipe ~40us + stores ~44us + VALU ~6us ADD (~120us observed) -> delete pipe
// demand: (a) constants in [q][r][4] lane-linear layout (m134's proven
// conflict-free b128 pattern), 2 rows/thread amortization; (b) phase 2
// sources w via v_readlane (registers, zero LDS) and x via 1 ds_read per
// row, stores 256B-contiguous dword per (row,rule); (c) second barrier
// deleted.  Phase-2 LDS: 130 instr/wave -> 4.
// Outputs flat: y[N], w[N*R], Phi[N*R*(D+1)] fp32 (bf16 fails threshold, R4).

constexpr int N_ROWS = 32768;
constexpr int D = 64;
constexpr int R = 32;
constexpr float EPS = 1e-12f;
constexpr int ROWS_PER_BLOCK = 16;
constexpr int BLOCK = 256;
constexpr int PHI_COLS = R * (D + 1);  // 2080
constexpr int NQ = D / 4;              // 16

typedef float f32x4 __attribute__((ext_vector_type(4)));

__device__ __forceinline__ float readlane_f(float v, int lane) {
    return __int_as_float(__builtin_amdgcn_readlane(__float_as_int(v), lane));
}

__global__ __launch_bounds__(BLOCK) void tsk_kernel(
    const float* __restrict__ Xz,
    const float* __restrict__ centers,
    const float* __restrict__ sigmas,
    const float* __restrict__ theta,
    float* __restrict__ y_out,
    float* __restrict__ w_out,
    float* __restrict__ phi_out)
{
    // [q][r][4]: lanes r=0..31 read 16B at dword addr q*128 + 4r -> lane-
    // linear stride-16B, the measured conflict-free b128 pattern (m134).
    __shared__ __align__(16) float cq[NQ][R][4];
    __shared__ __align__(16) float isq[NQ][R][4];
    __shared__ __align__(16) float thq[NQ][R][4];
    __shared__ float th0[R];
    __shared__ __align__(16) float x_lds[ROWS_PER_BLOCK][68];  // cols 0..63

    const int tid  = threadIdx.x;
    const int wv   = tid >> 6;    // wave 0..3, owns rows 4wv..4wv+3
    const int lane = tid & 63;
    const int h    = lane >> 5;   // half
    const int r    = lane & 31;   // rule
    const int row0 = blockIdx.x * ROWS_PER_BLOCK;

    // ---- stage constants, quad-interleaved (inv-sigma precomputed) ----
    for (int i = tid; i < R * D; i += BLOCK) {
        int q = i >> 7;
        int rem = i & 127;
        int rr = rem >> 2, j = rem & 3;
        int src = rr * D + (q << 2) + j;
        ((float*)cq)[i]  = centers[src];
        ((float*)isq)[i] = 1.0f / (sigmas[src] + EPS);
        ((float*)thq)[i] = theta[rr * (D + 1) + 1 + (q << 2) + j];
    }
    if (tid < R) th0[tid] = theta[tid * (D + 1)];

    // ---- stage 16 rows of x: 1024 floats = 256 float4, one per thread ----
    {
        const f32x4* x4 = (const f32x4*)(Xz + (size_t)row0 * D);
        f32x4 v = x4[tid];
        int rr = tid >> 4;
        int cc = (4 * tid) & 63;
        *(f32x4*)&x_lds[rr][cc] = v;
    }
    __syncthreads();

    // ---- phase 1: thread (wv,h,r) computes rows ra=4wv+2h, ra+1 ----
    const int ra = 4 * wv + 2 * h;
    float acc_a = 0.0f, acc_b = 0.0f;
    float td_a = th0[r];
    float td_b = td_a;
#pragma unroll
    for (int q = 0; q < NQ; ++q) {
        f32x4 cv = *(const f32x4*)&cq[q][r][0];
        f32x4 iv = *(const f32x4*)&isq[q][r][0];
        f32x4 tv = *(const f32x4*)&thq[q][r][0];
        f32x4 xa = *(const f32x4*)&x_lds[ra][4 * q];
        f32x4 xb = *(const f32x4*)&x_lds[ra + 1][4 * q];
#pragma unroll
        for (int j = 0; j < 4; ++j) {
            float za = (xa[j] - cv[j]) * iv[j];
            float zb = (xb[j] - cv[j]) * iv[j];
            acc_a = fmaf(za, za, acc_a);
            acc_b = fmaf(zb, zb, acc_b);
            td_a = fmaf(tv[j], xa[j], td_a);
            td_b = fmaf(tv[j], xb[j], td_b);
        }
    }
    float la = -0.5f * acc_a, lb = -0.5f * acc_b;

    // softmax over 32 rule-lanes per row (width 32 keeps halves separate)
    float ma = la, mb = lb;
#pragma unroll
    for (int off = 16; off >= 1; off >>= 1) {
        ma = fmaxf(ma, __shfl_xor(ma, off, 32));
        mb = fmaxf(mb, __shfl_xor(mb, off, 32));
    }
    float ea = __expf(la - ma), eb = __expf(lb - mb);
    float sa = ea, sb = eb;
#pragma unroll
    for (int off = 16; off >= 1; off >>= 1) {
        sa += __shfl_xor(sa, off, 32);
        sb += __shfl_xor(sb, off, 32);
    }
    float wa = ea / (sa + EPS);
    float wb = eb / (sb + EPS);

    // w_out: lanes (h,r) -> rows ra, ra+1, col r (contiguous 128B per half)
    w_out[(size_t)(row0 + ra) * R + r]     = wa;
    w_out[(size_t)(row0 + ra + 1) * R + r] = wb;

    // y = sum_r w_r * (theta_r . [1,x])
    float ya = wa * td_a, yb = wb * td_b;
#pragma unroll
    for (int off = 16; off >= 1; off >>= 1) {
        ya += __shfl_xor(ya, off, 32);
        yb += __shfl_xor(yb, off, 32);
    }
    if (r == 0) {
        y_out[row0 + ra]     = ya;
        y_out[row0 + ra + 1] = yb;
    }

    // NO second barrier: phase 2 reads only x_lds (written before barrier 1)
    // and wave-local registers.

    // ---- phase 2: register-fed store stream, wave owns rows 4wv..4wv+3 ----
    // w columns first: lanes (h,r) scatter w to Phi[row][r*65]
    {
        float* p0 = phi_out + (size_t)(row0 + ra) * PHI_COLS + r * 65;
        float* p1 = phi_out + (size_t)(row0 + ra + 1) * PHI_COLS + r * 65;
        *p0 = wa;
        *p1 = wb;
    }
    // x part: for each owned row, lane jj holds x[row][jj] in a register;
    // per rule: 64 lanes store 256B contiguous at Phi[row][r*65+1+jj].
    float xr[4];
#pragma unroll
    for (int rr = 0; rr < 4; ++rr)
        xr[rr] = x_lds[4 * wv + rr][lane];
#pragma unroll
    for (int rr = 0; rr < 4; ++rr) {
        float* prow = phi_out + (size_t)(row0 + 4 * wv + rr) * PHI_COLS + 1 + lane;
        const float xv = xr[rr];
        const int srclane = (rr >> 1) * 32;   // rows (rr>>1 half), reg (rr&1)
#pragma unroll
        for (int rl = 0; rl < R; ++rl) {
            float ws = readlane_f((rr & 1) ? wb : wa, srclane + rl);
            prow[rl * 65] = ws * xv;
        }
    }
}

extern "C" void kernel_launch(void* const* d_in, const int* in_sizes, int n_in,
                              void* d_out, int out_size, void* d_ws, size_t ws_size,
                              hipStream_t stream) {
    const float* Xz      = (const float*)d_in[0];
    const float* centers = (const float*)d_in[1];
    const float* sigmas  = (const float*)d_in[2];
    const float* theta   = (const float*)d_in[3];

    float* out = (float*)d_out;
    float* y_out   = out;
    float* w_out   = out + N_ROWS;
    float* phi_out = out + N_ROWS + (size_t)N_ROWS * R;

    dim3 grid(N_ROWS / ROWS_PER_BLOCK);
    tsk_kernel<<<grid, BLOCK, 0, stream>>>(Xz, centers, sigmas, theta,
                                           y_out, w_out, phi_out);
}